// Round 1
// baseline (868.503 us; speedup 1.0000x reference)
//
#include <hip/hip_runtime.h>
#include <hip/hip_bf16.h>

// Problem dims (fixed by reference)
#define B_  256
#define T_  250
#define D_  700
#define H_  1024
#define O_  20
#define KP  704          // K padded to multiple of 32 (22 K-steps of BK=32)

typedef __attribute__((ext_vector_type(8))) short bf16x8;
typedef __attribute__((ext_vector_type(4))) float f32x4;

// async global->LDS, 16B per lane (LDS dest = wave-uniform base + lane*16)
__device__ __forceinline__ void gl_lds16(const void* g, void* l) {
    __builtin_amdgcn_global_load_lds(
        (const __attribute__((address_space(1))) unsigned int*)g,
        (__attribute__((address_space(3))) unsigned int*)l, 16, 0, 0);
}

// ---------------------------------------------------------------------------
// Kernel A: split fp32 -> bf16 hi/lo, zero-padding K from Kin to Kout.
// Each thread handles 8 consecutive columns of one row.
// ---------------------------------------------------------------------------
__global__ void split_convert(const float* __restrict__ src,
                              unsigned short* __restrict__ hi,
                              unsigned short* __restrict__ lo,
                              int M, int Kin, int Kout)
{
    int idx = blockIdx.x * blockDim.x + threadIdx.x;
    int chunks = Kout >> 3;
    int total = M * chunks;
    if (idx >= total) return;
    int m  = idx / chunks;
    int c  = idx - m * chunks;
    int d0 = c << 3;
    unsigned short h8[8], l8[8];
#pragma unroll
    for (int e = 0; e < 8; ++e) {
        int d = d0 + e;
        float x = (d < Kin) ? src[(long)m * Kin + d] : 0.0f;
        __hip_bfloat16 h = __float2bfloat16(x);
        float hf = __bfloat162float(h);
        __hip_bfloat16 lv = __float2bfloat16(x - hf);
        h8[e] = *(unsigned short*)&h;
        l8[e] = *(unsigned short*)&lv;
    }
    long ob = (long)m * Kout + d0;
    *(uint4*)(hi + ob) = *(uint4*)h8;
    *(uint4*)(lo + ob) = *(uint4*)l8;
}

// ---------------------------------------------------------------------------
// Kernel B: split-bf16 GEMM  C[m,n] = sum_k A[m,k]*B[n,k] + bias[n]
// A = Xhi/Xlo [M, KP], B = W1hi/W1lo [H, KP] (both K-major), C = d1 [M, H] f32.
// 128x128 tile, BK=32, 256 threads (2x2 waves, each 64x64 = 4x4 frags of
// 16x16x32). Three MFMA passes per K-step: hi*hi + hi*lo + lo*hi.
// ---------------------------------------------------------------------------
__global__ __launch_bounds__(256, 2) void gemm_split(
    const unsigned short* __restrict__ Ahi, const unsigned short* __restrict__ Alo,
    const unsigned short* __restrict__ Bhi, const unsigned short* __restrict__ Blo,
    const float* __restrict__ bias, float* __restrict__ C)
{
    __shared__ __align__(16) unsigned short sAh[128 * 32];
    __shared__ __align__(16) unsigned short sAl[128 * 32];
    __shared__ __align__(16) unsigned short sBh[128 * 32];
    __shared__ __align__(16) unsigned short sBl[128 * 32];

    const int t    = threadIdx.x;
    const int nblk = blockIdx.x;   // 0..7   (N fastest -> A-tile reuse in L2/L3)
    const int mblk = blockIdx.y;   // 0..499
    const int wave = t >> 6, lane = t & 63;
    const int wr = wave >> 1, wc = wave & 1;

    f32x4 acc[4][4];
#pragma unroll
    for (int i = 0; i < 4; ++i)
#pragma unroll
        for (int j = 0; j < 4; ++j) acc[i][j] = (f32x4){0.f, 0.f, 0.f, 0.f};

    // staging addresses: thread t loads row t/4, cols (t%4)*8 .. +8 (16 B)
    const long arow = (long)(mblk * 128 + (t >> 2)) * KP + (t & 3) * 8;
    const long brow = (long)(nblk * 128 + (t >> 2)) * KP + (t & 3) * 8;
    const int  l8   = t * 8;          // LDS element offset, issue 0 (rows 0..63)

    const int fr = lane & 15;
    const int fk = (lane >> 4) * 8;

    for (int ks = 0; ks < KP; ks += 32) {
        __syncthreads();              // previous iteration's LDS reads done
        gl_lds16(Ahi + arow + ks, &sAh[l8]);
        gl_lds16(Ahi + arow + 64 * KP + ks, &sAh[2048 + l8]);
        gl_lds16(Alo + arow + ks, &sAl[l8]);
        gl_lds16(Alo + arow + 64 * KP + ks, &sAl[2048 + l8]);
        gl_lds16(Bhi + brow + ks, &sBh[l8]);
        gl_lds16(Bhi + brow + 64 * KP + ks, &sBh[2048 + l8]);
        gl_lds16(Blo + brow + ks, &sBl[l8]);
        gl_lds16(Blo + brow + 64 * KP + ks, &sBl[2048 + l8]);
        __syncthreads();              // staging complete (vmcnt drained)

        bf16x8 ah[4], al[4], bh[4], bl[4];
#pragma unroll
        for (int i = 0; i < 4; ++i) {
            ah[i] = *(const bf16x8*)&sAh[(wr * 64 + i * 16 + fr) * 32 + fk];
            al[i] = *(const bf16x8*)&sAl[(wr * 64 + i * 16 + fr) * 32 + fk];
            bh[i] = *(const bf16x8*)&sBh[(wc * 64 + i * 16 + fr) * 32 + fk];
            bl[i] = *(const bf16x8*)&sBl[(wc * 64 + i * 16 + fr) * 32 + fk];
        }
#pragma unroll
        for (int i = 0; i < 4; ++i)
#pragma unroll
            for (int j = 0; j < 4; ++j)
                acc[i][j] = __builtin_amdgcn_mfma_f32_16x16x32_bf16(ah[i], bh[j], acc[i][j], 0, 0, 0);
#pragma unroll
        for (int i = 0; i < 4; ++i)
#pragma unroll
            for (int j = 0; j < 4; ++j)
                acc[i][j] = __builtin_amdgcn_mfma_f32_16x16x32_bf16(ah[i], bl[j], acc[i][j], 0, 0, 0);
#pragma unroll
        for (int i = 0; i < 4; ++i)
#pragma unroll
            for (int j = 0; j < 4; ++j)
                acc[i][j] = __builtin_amdgcn_mfma_f32_16x16x32_bf16(al[i], bh[j], acc[i][j], 0, 0, 0);
    }

    // epilogue: C/D layout col=lane&15, row=(lane>>4)*4+reg  [m89-verified]
    const int r0 = mblk * 128 + wr * 64 + (lane >> 4) * 4;
    const int c0 = nblk * 128 + wc * 64 + (lane & 15);
#pragma unroll
    for (int j = 0; j < 4; ++j) {
        int col = c0 + j * 16;
        float bv = bias[col];
#pragma unroll
        for (int i = 0; i < 4; ++i) {
            int row = r0 + i * 16;
#pragma unroll
            for (int r = 0; r < 4; ++r)
                C[(long)(row + r) * H_ + col] = acc[i][j][r] + bv;
        }
    }
}

// ---------------------------------------------------------------------------
// Kernel C: sequential LIF scan. One block (256 threads) per batch row.
// Thread t owns neurons 4t..4t+3 (mem1/spk in regs). W2 held in registers:
// wave w owns outputs 5w..5w+4, lane owns h = 16*lane..+15. Spikes exchanged
// through LDS; d2 wave-reduced; softmax/acc in wave 0 lanes 0..19.
// ---------------------------------------------------------------------------
__global__ __launch_bounds__(256, 1) void snn_scan(
    const float* __restrict__ d1,   // [B*T, H]
    const float* __restrict__ tau1, const float* __restrict__ W2,
    const float* __restrict__ b2,   const float* __restrict__ tau2,
    float* __restrict__ out)
{
    __shared__ __align__(16) float sspk[H_];
    __shared__ float sd2[32];

    const int b = blockIdx.x;
    const int t = threadIdx.x;
    const int wave = t >> 6, lane = t & 63;

    // layer-1 per-neuron state
    float a1[4], om1[4], mem1[4] = {0, 0, 0, 0}, spk[4] = {0, 0, 0, 0};
#pragma unroll
    for (int e = 0; e < 4; ++e) {
        float tv = tau1[4 * t + e];
        a1[e]  = 1.0f / (1.0f + __expf(-tv));
        om1[e] = 1.0f - a1[e];
    }

    // W2 fragment in registers: 5 outputs x 16 columns
    float w2r[5][16];
#pragma unroll
    for (int oo = 0; oo < 5; ++oo)
#pragma unroll
        for (int q = 0; q < 4; ++q)
            *(float4*)&w2r[oo][4 * q] =
                *(const float4*)&W2[(wave * 5 + oo) * H_ + lane * 16 + 4 * q];

    // readout state (wave 0, lanes 0..19)
    float mem2 = -1e30f, accv = 0.f, a2 = 0.f, om2 = 0.f, b2v = 0.f;
    if (wave == 0 && lane < O_) {
        float tv = tau2[lane];
        a2 = 1.0f / (1.0f + __expf(-tv));
        om2 = 1.0f - a2;
        b2v = b2[lane];
        mem2 = 0.f;
    }

    const float* drow = d1 + (long)b * T_ * H_ + 4 * t;
    float4 cur = *(const float4*)drow;

    for (int ts = 0; ts < T_; ++ts) {
        float4 nxt = make_float4(0.f, 0.f, 0.f, 0.f);
        if (ts + 1 < T_) nxt = *(const float4*)(drow + (long)(ts + 1) * H_);

        // LIF layer 1 (soft reset uses previous spike of the SAME neuron)
        float c4[4] = {cur.x, cur.y, cur.z, cur.w};
#pragma unroll
        for (int e = 0; e < 4; ++e) {
            mem1[e] = mem1[e] * a1[e] + om1[e] * c4[e] - spk[e];
            spk[e]  = (mem1[e] > 1.0f) ? 1.0f : 0.0f;
        }
        *(float4*)&sspk[4 * t] = make_float4(spk[0], spk[1], spk[2], spk[3]);
        __syncthreads();

        // d2 partials from register W2
        float s16[16];
#pragma unroll
        for (int q = 0; q < 4; ++q)
            *(float4*)&s16[4 * q] = *(const float4*)&sspk[lane * 16 + 4 * q];
        float p[5] = {0.f, 0.f, 0.f, 0.f, 0.f};
#pragma unroll
        for (int oo = 0; oo < 5; ++oo)
#pragma unroll
            for (int k = 0; k < 16; ++k)
                p[oo] += s16[k] * w2r[oo][k];
#pragma unroll
        for (int m = 1; m < 64; m <<= 1)
#pragma unroll
            for (int oo = 0; oo < 5; ++oo)
                p[oo] += __shfl_xor(p[oo], m, 64);
        if (lane == 0) {
#pragma unroll
            for (int oo = 0; oo < 5; ++oo) sd2[wave * 5 + oo] = p[oo];
        }
        __syncthreads();

        // readout + online softmax accumulation (wave 0 only)
        if (wave == 0) {
            if (lane < O_) {
                float d2v = sd2[lane] + b2v;
                mem2 = mem2 * a2 + om2 * d2v;
            }
            float mv = mem2;                       // lanes >=20 hold -1e30
#pragma unroll
            for (int m = 1; m < 64; m <<= 1)
                mv = fmaxf(mv, __shfl_xor(mv, m, 64));
            float ev = (lane < O_) ? __expf(mem2 - mv) : 0.f;
            float sum = ev;
#pragma unroll
            for (int m = 1; m < 64; m <<= 1)
                sum += __shfl_xor(sum, m, 64);
            if (ts > 10 && lane < O_) accv += ev / sum;
        }
        cur = nxt;
    }

    if (wave == 0 && lane < O_) out[b * O_ + lane] = accv;
}

// ---------------------------------------------------------------------------
extern "C" void kernel_launch(void* const* d_in, const int* in_sizes, int n_in,
                              void* d_out, int out_size, void* d_ws, size_t ws_size,
                              hipStream_t stream)
{
    const float* X    = (const float*)d_in[0];   // [B,T,D]
    const float* W1   = (const float*)d_in[1];   // [H,D]
    const float* b1   = (const float*)d_in[2];   // [H]
    const float* tau1 = (const float*)d_in[3];   // [H]
    const float* W2   = (const float*)d_in[4];   // [O,H]
    const float* b2   = (const float*)d_in[5];   // [O]
    const float* tau2 = (const float*)d_in[6];   // [O]
    float* out = (float*)d_out;

    const long M = (long)B_ * T_;                // 64000
    unsigned short* Xhi  = (unsigned short*)d_ws;
    unsigned short* Xlo  = Xhi + M * KP;
    unsigned short* W1hi = Xlo + M * KP;
    unsigned short* W1lo = W1hi + (long)H_ * KP;
    float* d1 = (float*)(W1lo + (long)H_ * KP);  // [M, H] fp32
    // total ws: 2*M*KP*2 + 2*H*KP*2 + M*H*4 = ~425 MiB

    // 1. split conversions
    {
        int chunks = (int)M * (KP / 8);          // 5,632,000
        split_convert<<<(chunks + 255) / 256, 256, 0, stream>>>(X, Xhi, Xlo, (int)M, D_, KP);
    }
    {
        int chunks = H_ * (KP / 8);              // 90,112
        split_convert<<<(chunks + 255) / 256, 256, 0, stream>>>(W1, W1hi, W1lo, H_, D_, KP);
    }

    // 2. d1 = X @ W1^T + b1   (split-bf16 MFMA, ~fp32 accuracy)
    {
        dim3 grid(H_ / 128, (int)(M / 128));     // (8, 500), N fastest
        gemm_split<<<grid, 256, 0, stream>>>(Xhi, Xlo, W1hi, W1lo, b1, d1);
    }

    // 3. sequential scan, one block per batch row
    snn_scan<<<B_, 256, 0, stream>>>(d1, tau1, W2, b2, tau2, out);
}